// Round 1
// baseline (447.844 us; speedup 1.0000x reference)
//
#include <hip/hip_runtime.h>

// Problem geometry (fixed by the reference module config)
#define BATCH 64
#define IC    64
#define IH    64
#define IW    64
#define OC    256
#define OH    65
#define OW    65
#define NTAP  4          // KH*KW = 2*2
#define LROW  (IW + 2)   // staged row width: cols -1..64 (zero-padded)

// ---------------------------------------------------------------------------
// Prolog: recover the one-hot selection indices from the weight tensor.
// weight layout (O, I, KH, KW) flat = o*256 + i*4 + (kh*2+kw).
// For each (o, p) there is exactly one i with weight==1.
// ---------------------------------------------------------------------------
__global__ void build_idx_kernel(const float* __restrict__ w,
                                 int* __restrict__ idx) {
    int t = blockIdx.x * blockDim.x + threadIdx.x;   // 0 .. 1023
    if (t >= OC * NTAP) return;
    int o = t >> 2;
    int p = t & 3;
    const float* wo = w + o * (IC * NTAP) + p;
    int found = 0;
    for (int i = 0; i < IC; ++i) {
        if (wo[i * NTAP] > 0.5f) found = i;
    }
    idx[t] = found;
}

// ---------------------------------------------------------------------------
// Main: one block per (output-row y, batch b). Stage the two input rows
// (y-1, y) for all 64 channels into LDS with zero padding, then each
// thread sweeps (o, x) pairs: out = 4 LDS gathers + 3 adds.
// ---------------------------------------------------------------------------
__global__ __launch_bounds__(256) void spl_kernel(
        const float* __restrict__ x,
        const int*   __restrict__ idx_g,
        float*       __restrict__ out) {
    __shared__ float lds[2][IC][LROW];   // 2*64*66*4 = 33792 B
    __shared__ int   idx_s[OC * NTAP];   // 4096 B

    const int y   = blockIdx.x;          // 0..64 (output row)
    const int b   = blockIdx.y;          // 0..63
    const int tid = threadIdx.x;

    // idx table -> LDS
    for (int i = tid; i < OC * NTAP; i += 256) idx_s[i] = idx_g[i];

    // Stage rows (input coords y-1 and y), zero-padded cols [-1, 65).
    // 2*64*66 = 8448 elements; consecutive tids hit consecutive cols
    // within a channel -> coalesced 256 B global segments.
    for (int e = tid; e < 2 * IC * LROW; e += 256) {
        int r    = e / (IC * LROW);
        int rem  = e - r * (IC * LROW);
        int c    = rem / LROW;
        int col  = rem - c * LROW;
        int inrow = y + r - 1;           // -1 .. 65
        int incol = col - 1;             // -1 .. 65
        float v = 0.0f;
        if ((unsigned)inrow < (unsigned)IH && (unsigned)incol < (unsigned)IW)
            v = x[((b * IC + c) * IH + inrow) * IW + incol];
        lds[r][c][col] = v;
    }
    __syncthreads();

    // Sweep all (o, x): 256*65 = 16640 outputs, 65 per thread.
    // Stores: lanes with the same o write consecutive x -> contiguous
    // 260 B runs per o-row of out[b][o][y][:].
    for (int i = tid; i < OC * OW; i += 256) {
        int o  = i / OW;
        int xx = i - o * OW;
        const int* ip = &idx_s[o * NTAP];
        // tap (kh,kw): lds[kh][idx[o][kh*2+kw]][xx + kw]
        float s = lds[0][ip[0]][xx]     + lds[0][ip[1]][xx + 1]
                + lds[1][ip[2]][xx]     + lds[1][ip[3]][xx + 1];
        out[(((size_t)b * OC + o) * OH + y) * OW + xx] = s;
    }
}

extern "C" void kernel_launch(void* const* d_in, const int* in_sizes, int n_in,
                              void* d_out, int out_size, void* d_ws, size_t ws_size,
                              hipStream_t stream) {
    const float* x = (const float*)d_in[0];
    const float* w = (const float*)d_in[1];
    float* out     = (float*)d_out;
    int*   idx     = (int*)d_ws;         // 256*4 ints = 4 KB scratch

    build_idx_kernel<<<(OC * NTAP + 255) / 256, 256, 0, stream>>>(w, idx);

    dim3 grid(OH, BATCH);                // 65 x 64 = 4160 blocks
    spl_kernel<<<grid, 256, 0, stream>>>(x, idx, out);
}

// Round 2
// 426.674 us; speedup vs baseline: 1.0496x; 1.0496x over previous
//
#include <hip/hip_runtime.h>

// Problem geometry (fixed by the reference module config)
#define BATCH 64
#define IC    64
#define IH    64
#define IW    64
#define OC    256
#define OH    65
#define OW    65
#define NTAP  4          // KH*KW = 2*2
#define PLANE (OH * OW)  // 4225 outputs per (b, o)

// ---------------------------------------------------------------------------
// One block per (o, b). The 2x2 "conv" with a one-hot selection mask is just
//   out[b,o,y,x] = x[b,i00,y-1,x-1] + x[b,i01,y-1,x]
//                + x[b,i10,y,  x-1] + x[b,i11,y,  x]      (zero when OOB)
// where i_p = the single input channel with weight 1 for tap p.
// Block recovers its own 4 indices from a coalesced 1 KB read of w[o],
// then sweeps its contiguous 16.9 KB output plane. Input (64 MB) and
// weight (256 KB) are L2/L3 resident; writes dominate HBM traffic.
// ---------------------------------------------------------------------------
__global__ __launch_bounds__(256) void spl_kernel(
        const float* __restrict__ x,
        const float* __restrict__ w,
        float*       __restrict__ out) {
    const int o = blockIdx.x;        // 0..255
    const int b = blockIdx.y;        // 0..63
    const int t = threadIdx.x;       // 0..255

    // --- recover the 4 one-hot channel indices for this o -----------------
    // w[o] is IC*NTAP = 256 floats, flat index t = i*4 + p. Exactly one
    // thread per p sees 1.0f.
    __shared__ int idx_s[NTAP];
    float wv = w[o * (IC * NTAP) + t];          // coalesced 1 KB / block
    if (wv > 0.5f) idx_s[t & 3] = t >> 2;
    __syncthreads();

    const size_t bbase = (size_t)b * IC * (IH * IW);
    const float* p00 = x + bbase + (size_t)idx_s[0] * (IH * IW);
    const float* p01 = x + bbase + (size_t)idx_s[1] * (IH * IW);
    const float* p10 = x + bbase + (size_t)idx_s[2] * (IH * IW);
    const float* p11 = x + bbase + (size_t)idx_s[3] * (IH * IW);
    float* po = out + ((size_t)b * OC + o) * PLANE;

    // --- sweep the 65x65 output plane: i = y*65 + x -----------------------
    // k = 0..15: i = t + k*256 <= 4095 < 4225, always in range.
    #pragma unroll 4
    for (int k = 0; k < 16; ++k) {
        int i = t + k * 256;
        int y  = (i * 4033) >> 18;               // i / 65 for i < 4225
        int xx = i - y * 65;
        int off = (y << 6) + xx;                 // y*64 + x
        bool yl = (y  >= 1), yh = (y  <= 63);
        bool xl = (xx >= 1), xh = (xx <= 63);
        float t00 = (yl && xl) ? p00[off - 65] : 0.0f;
        float t01 = (yl && xh) ? p01[off - 64] : 0.0f;
        float t10 = (yh && xl) ? p10[off - 1]  : 0.0f;
        float t11 = (yh && xh) ? p11[off]      : 0.0f;
        po[i] = (t00 + t01) + (t10 + t11);
    }
    // tail: i = t + 4096, valid for t < 129
    {
        int i = t + 4096;
        if (i < PLANE) {
            int y  = (i * 4033) >> 18;
            int xx = i - y * 65;
            int off = (y << 6) + xx;
            bool yl = (y  >= 1), yh = (y  <= 63);
            bool xl = (xx >= 1), xh = (xx <= 63);
            float t00 = (yl && xl) ? p00[off - 65] : 0.0f;
            float t01 = (yl && xh) ? p01[off - 64] : 0.0f;
            float t10 = (yh && xl) ? p10[off - 1]  : 0.0f;
            float t11 = (yh && xh) ? p11[off]      : 0.0f;
            po[i] = (t00 + t01) + (t10 + t11);
        }
    }
}

extern "C" void kernel_launch(void* const* d_in, const int* in_sizes, int n_in,
                              void* d_out, int out_size, void* d_ws, size_t ws_size,
                              hipStream_t stream) {
    const float* x = (const float*)d_in[0];
    const float* w = (const float*)d_in[1];
    float* out     = (float*)d_out;

    dim3 grid(OC, BATCH);            // o fast (same-b blocks adjacent), b slow
    spl_kernel<<<grid, 256, 0, stream>>>(x, w, out);
}

// Round 3
// 409.457 us; speedup vs baseline: 1.0938x; 1.0420x over previous
//
#include <hip/hip_runtime.h>

// Problem geometry (fixed by the reference module config)
#define BATCH 64
#define IC    64
#define IH    64
#define IW    64
#define OC    256
#define OH    65
#define OW    65
#define NTAP  4
#define PLANE (OH * OW)      // 4225 outputs per (b, o)
#define TASKS (OH * 17)      // 65 rows x 17 four-wide chunks = 1105

// Unaligned float4 ld/st (addresses are 4B-aligned only; gfx950 supports
// unaligned dwordx4 — memcpy tells clang the真 alignment legally).
__device__ __forceinline__ float4 ld4u(const float* p) {
    float4 v; __builtin_memcpy(&v, p, 16); return v;
}
__device__ __forceinline__ void st4u(float* p, float4 v) {
    __builtin_memcpy(p, &v, 16);
}

// out[b,o,y,x] = x[b,i00,y-1,x-1] + x[b,i01,y-1,x]
//             + x[b,i10,y,  x-1] + x[b,i11,y,  x]   (zero when OOB)
// One block per (b,o) plane. Row masks via clamp+multiply (no exec-mask
// predication); x handled in 4-wide float4 chunks (17 per row, chunk 16
// is the single x=64 column).
__global__ __launch_bounds__(256) void spl_kernel(
        const float* __restrict__ x,
        const float* __restrict__ w,
        float*       __restrict__ out) {
    // XCD-aware decode: all 256 o-blocks of one batch b land on one XCD
    // (wg%8 round-robin heuristic), with o consecutive inside the XCD.
    unsigned wg  = blockIdx.x;
    unsigned xcd = wg & 7u;
    unsigned l   = wg >> 3;            // 0..2047
    unsigned o   = l & 255u;           // 0..255
    unsigned b   = ((l >> 8) << 3) | xcd;  // 0..63

    const int t = threadIdx.x;

    // Recover the 4 one-hot channel indices for this o from w[o] (1 KB).
    __shared__ int idx_s[NTAP];
    float wv = w[o * (IC * NTAP) + t];     // flat = i*4 + p
    if (wv > 0.5f) idx_s[t & 3] = t >> 2;
    __syncthreads();

    const size_t bbase = (size_t)b * IC * (IH * IW);
    const float* p00 = x + bbase + (size_t)idx_s[0] * (IH * IW);
    const float* p01 = x + bbase + (size_t)idx_s[1] * (IH * IW);
    const float* p10 = x + bbase + (size_t)idx_s[2] * (IH * IW);
    const float* p11 = x + bbase + (size_t)idx_s[3] * (IH * IW);
    float* po = out + ((size_t)b * OC + o) * PLANE;

    for (int base = 0; base < TASKS; base += 256) {
        int i = base + t;
        if (i >= TASKS) break;
        int y = (i * 3856) >> 16;          // i / 17, exact for i < 1105
        int c = i - y * 17;                // chunk in row: 0..16

        // Row predication: clamp row index, zero via multiply.
        int   topr = (y >= 1)  ? (y - 1) : 0;
        int   botr = (y <= 63) ? y       : 63;
        float mt   = (y >= 1)  ? 1.0f : 0.0f;
        float mb   = (y <= 63) ? 1.0f : 0.0f;
        int to = topr << 6;                // *IW
        int bo = botr << 6;

        if (c < 16) {
            int x0  = c << 2;                       // 0,4,...,60
            int xm1 = (c == 0) ? 0 : (x0 - 1);      // left-tap col base
            float4 tl = ld4u(p00 + to + xm1);
            float4 tr = ld4u(p01 + to + x0);
            float4 bl = ld4u(p10 + bo + xm1);
            float4 br = ld4u(p11 + bo + x0);
            if (c == 0) {                           // cols {-1,0,1,2}
                tl = make_float4(0.f, tl.x, tl.y, tl.z);
                bl = make_float4(0.f, bl.x, bl.y, bl.z);
            }
            float4 r;
            r.x = mt * (tl.x + tr.x) + mb * (bl.x + br.x);
            r.y = mt * (tl.y + tr.y) + mb * (bl.y + br.y);
            r.z = mt * (tl.z + tr.z) + mb * (bl.z + br.z);
            r.w = mt * (tl.w + tr.w) + mb * (bl.w + br.w);
            st4u(po + y * OW + x0, r);
        } else {
            // x = 64: right taps OOB (0); left taps read col 63.
            po[y * OW + 64] = mt * p00[to + 63] + mb * p10[bo + 63];
        }
    }
}

extern "C" void kernel_launch(void* const* d_in, const int* in_sizes, int n_in,
                              void* d_out, int out_size, void* d_ws, size_t ws_size,
                              hipStream_t stream) {
    const float* x = (const float*)d_in[0];
    const float* w = (const float*)d_in[1];
    float* out     = (float*)d_out;

    spl_kernel<<<OC * BATCH, 256, 0, stream>>>(x, w, out);
}